// Round 10
// baseline (593.669 us; speedup 1.0000x reference)
//
#include <hip/hip_runtime.h>
#include <hip/hip_fp16.h>
#include <cstdint>
#include <cstring>

// VQR circuit simulator: 16 qubits, B=512, 4 layers.
// CNOTs are GF(2) index-relabeling bookkeeping. Fused 1q gates (SU(2)) are
// XOR-mask pair rotations, scheduled into 2 window passes
// (gen+gates+store, load+gates+measure). Within a pass, bundles of <=4
// SAME-LAYER mask-independent gates (flip==0 => packed v_pk_fma_f32 path,
// 8 pk-FMA/pair). LDS uses a GF(2)-linear XOR swizzle
// swz(x)=x^((x>>4)&15)^((x>>8)&15): XOR-cosets stay cosets, and every wave
// access projects at full rank onto the bank bits -> minimum bank conflicts
// regardless of bundle composition.

typedef float v2f __attribute__((ext_vector_type(2)));

struct BundleMeta {
    uint16_t voff[16];   // coset offsets (local 12-bit index space)
    uint16_t row[4];     // branch parity masks (local bits), per slot
    uint16_t flip[4];    // flip[g] bit t = parity(voff[t] & row[g]); 0 => packed path
    uint8_t  piv[4];     // pivot bit positions, ASCENDING (rep expansion)
    uint8_t  gidx[4];    // gate coefficient index l*16+w; 0xFF = identity pad
    uint8_t  nl[4];      // branch parity masks over the 4 chunk bits
};

struct PassMeta {
    int       nbundles;
    BundleMeta bd[24];
    uint8_t   gap[4];          // non-local bit positions, ASCENDING (all >=8)
    uint8_t   nlw[4];          // chunk bit k -> wire
    uint8_t   wire_of_bit[12]; // packed LDS bit -> wire (product-state init)
    uint16_t  meas_row;        // measurement parity mask (local bits)
    uint8_t   meas_nl;         // measurement parity mask (chunk bits)
};

__device__ __forceinline__ float2 cmul2(float2 a, float2 b) {
    return make_float2(a.x * b.x - a.y * b.y, a.x * b.y + a.y * b.x);
}
__device__ __forceinline__ float xorf(float a, unsigned s) {
    return __uint_as_float(__float_as_uint(a) ^ s);
}
// GF(2)-linear LDS swizzle: full-rank projection of any bit window onto banks.
__device__ __forceinline__ unsigned swz(unsigned x) {
    return x ^ ((x >> 4) & 15u) ^ ((x >> 8) & 15u);
}

// MODE 0: coef + product state + gates + store (fp16)
// MODE 1: coef + load + gates + store (in-place, fp16)
// MODE 2: coef + load + gates + measurement reduce (no store)
template <int MODE>
__global__ __launch_bounds__(256, 4)
void pass_kernel(const float* __restrict__ X, const float* __restrict__ Wt,
                 const float* __restrict__ Bs, __half2* __restrict__ state,
                 float* __restrict__ out, PassMeta meta)
{
    __shared__ v2f    amp[4096];   // 32 KiB, AoS (re,im), swizzled addressing
    __shared__ float4 coef[64];    // 1 KiB  (SU(2) (a,b) per gate)
    const int tid = threadIdx.x;
    const int bb  = blockIdx.x >> 4;
    const unsigned c = blockIdx.x & 15u;
    const size_t base = (size_t)bb << 16;

    // ---- in-block coefficients: U = Rz(t2)Ry(t1)Rz(t0)Rx(2atan x), SU(2) (a,b)
    if (tid < 64) {
        int l = tid >> 4, w = tid & 15;
        float x  = X[bb * 16 + w];
        float ce = 1.0f / sqrtf(1.0f + x * x);
        float se = x * ce;
        float t0 = 0.5f * Wt[(l * 16 + w) * 3 + 0];
        float t1 = 0.5f * Wt[(l * 16 + w) * 3 + 1];
        float t2 = 0.5f * Wt[(l * 16 + w) * 3 + 2];
        float c1 = cosf(t1), s1 = sinf(t1);
        float ca = cosf(t0 + t2), sa = sinf(t0 + t2);
        float cb = cosf(t2 - t0), sb = sinf(t2 - t0);
        float2 W00 = make_float2( c1 * ca, -c1 * sa);
        float2 W01 = make_float2(-s1 * cb,  s1 * sb);
        float2 a  = make_float2(W00.x * ce + W01.y * se, W00.y * ce - W01.x * se);
        float2 b2 = make_float2(W00.y * se + W01.x * ce, -W00.x * se + W01.y * ce);
        coef[tid] = make_float4(a.x, a.y, b2.x, b2.y);
    }
    if (MODE == 0 && c == 0 && tid == 64) out[bb] = Bs[0];  // bias init

    auto expand = [&](unsigned x) -> unsigned {   // gaps ascending, all >= 8
        #pragma unroll
        for (int k = 0; k < 4; ++k) {
            unsigned g = meta.gap[k];
            x = ((x >> g) << (g + 1)) | (x & ((1u << g) - 1u)) | (((c >> k) & 1u) << g);
        }
        return x;
    };

    if constexpr (MODE == 0) {
        __syncthreads();   // coef ready
        if (tid == 0) {
            float2 k = make_float2(1.f, 0.f);
            #pragma unroll
            for (int t = 0; t < 4; ++t) {
                float4 u = coef[meta.nlw[t]];
                float2 col = ((c >> t) & 1u) ? make_float2(-u.z, u.w)
                                             : make_float2(u.x, u.y);
                k = cmul2(k, col);
            }
            amp[0] = v2f{k.x, k.y};   // swz(0)==0
        }
        __syncthreads();
        for (int s = 0; s < 12; ++s) {
            const int n = 1 << s;
            float4 u = coef[meta.wire_of_bit[s]];
            const float2 c0 = make_float2(u.x, u.y);
            const float2 c1 = make_float2(-u.z, u.w);
            const unsigned sn = swz((unsigned)n);   // i<n => i+n == i^n; linear
            for (int i = tid; i < n; i += 256) {
                unsigned si = swz((unsigned)i);
                v2f av = amp[si];
                float2 a = make_float2(av.x, av.y);
                float2 h = cmul2(a, c1);
                float2 l = cmul2(a, c0);
                amp[si ^ sn] = v2f{h.x, h.y};
                amp[si]      = v2f{l.x, l.y};
            }
            __syncthreads();
        }
    } else {
        #pragma unroll
        for (int it = 0; it < 4; ++it) {
            unsigned u = (unsigned)(tid + it * 256) * 4u;
            unsigned a = expand(u);
            unsigned su = swz(u);   // swz(u+k) == swz(u)^k for k<4 (u 4-aligned)
            uint4 v = *reinterpret_cast<const uint4*>(state + base + a);
            float2 f0 = __half22float2(__builtin_bit_cast(__half2, v.x));
            float2 f1 = __half22float2(__builtin_bit_cast(__half2, v.y));
            float2 f2 = __half22float2(__builtin_bit_cast(__half2, v.z));
            float2 f3 = __half22float2(__builtin_bit_cast(__half2, v.w));
            amp[su]      = v2f{f0.x, f0.y};
            amp[su ^ 1u] = v2f{f1.x, f1.y};
            amp[su ^ 2u] = v2f{f2.x, f2.y};
            amp[su ^ 3u] = v2f{f3.x, f3.y};
        }
        __syncthreads();   // also covers coef staging
    }

    for (int ci = 0; ci < meta.nbundles; ++ci) {
        const BundleMeta& B = meta.bd[ci];
        unsigned r = (unsigned)tid;
        #pragma unroll
        for (int k = 0; k < 4; ++k) {
            unsigned p = B.piv[k];
            r = ((r >> p) << (p + 1)) | (r & ((1u << p) - 1u));
        }
        const unsigned sr = swz(r);
        v2f a[16];
        #pragma unroll
        for (int t = 0; t < 16; ++t) a[t] = amp[sr ^ swz((unsigned)B.voff[t])];
        #pragma unroll
        for (int g = 0; g < 4; ++g) {
            if (B.gidx[g] == 0xFF) continue;       // identity pad (uniform skip)
            const float4 uv = coef[B.gidx[g]];
            const unsigned sb31 =
                ((unsigned)((__popc(r & (unsigned)B.row[g]) +
                             __popc((unsigned)B.nl[g] & c)) & 1)) << 31;
            const float ai_s = xorf(uv.y, sb31);
            const float br_s = xorf(uv.z, sb31);
            if (B.flip[g] == 0) {
                // packed path: x*P = xr*P + {-xi,xi}*swap(P)
                const float AR = uv.x;
                const v2f V1 = { xorf(ai_s, 0x80000000u), ai_s };
                const v2f V2 = { xorf(uv.w, 0x80000000u), uv.w };
                #pragma unroll
                for (int k = 0; k < 8; ++k) {
                    const int t  = ((k >> g) << (g + 1)) | (k & ((1 << g) - 1));
                    const int t2 = t | (1 << g);
                    const v2f P = a[t], Q = a[t2];
                    const v2f Psw = __builtin_shufflevector(P, P, 1, 0);
                    const v2f Qsw = __builtin_shufflevector(Q, Q, 1, 0);
                    v2f np = AR * P + V1 * Psw + br_s * Q + V2 * Qsw;
                    v2f nq = AR * Q - V1 * Qsw - br_s * P + V2 * Psw;
                    a[t] = np; a[t2] = nq;
                }
            } else {
                // scalar fallback (dirty pads only)
                const unsigned fl = B.flip[g];
                #pragma unroll
                for (int t = 0; t < 16; ++t) {
                    if (t & (1 << g)) continue;
                    const int t2 = t | (1 << g);
                    const unsigned fb = (fl << (31 - t)) & 0x80000000u;
                    const float tai = xorf(ai_s, fb);
                    const float tbr = xorf(br_s, fb);
                    const float pr = a[t].x,  pi = a[t].y;
                    const float qr = a[t2].x, qi = a[t2].y;
                    const float npr = __builtin_fmaf(uv.x, pr,
                                      __builtin_fmaf(-tai, pi,
                                      __builtin_fmaf(tbr, qr, -uv.w * qi)));
                    const float npi = __builtin_fmaf(uv.x, pi,
                                      __builtin_fmaf( tai, pr,
                                      __builtin_fmaf(tbr, qi,  uv.w * qr)));
                    const float nqr = __builtin_fmaf(-tbr, pr,
                                      __builtin_fmaf(-uv.w, pi,
                                      __builtin_fmaf(uv.x, qr,  tai * qi)));
                    const float nqi = __builtin_fmaf(-tbr, pi,
                                      __builtin_fmaf( uv.w, pr,
                                      __builtin_fmaf(uv.x, qi, -tai * qr)));
                    a[t]  = v2f{npr, npi};
                    a[t2] = v2f{nqr, nqi};
                }
            }
        }
        if (MODE == 2 && ci == meta.nbundles - 1) {
            // measure directly from registers (skip final LDS round-trip)
            float acc = 0.f;
            const unsigned mcp = (unsigned)(__popc((unsigned)meta.meas_nl & c) & 1);
            #pragma unroll
            for (int t = 0; t < 16; ++t) {
                float pr = __builtin_fmaf(a[t].x, a[t].x, a[t].y * a[t].y);
                unsigned sg = ((unsigned)__popc((r ^ B.voff[t]) &
                               (unsigned)meta.meas_row) & 1u) ^ mcp;
                acc += sg ? -pr : pr;
            }
            for (int off = 32; off > 0; off >>= 1) acc += __shfl_down(acc, off, 64);
            if ((tid & 63) == 0) atomicAdd(&out[bb], acc);
            return;
        }
        #pragma unroll
        for (int t = 0; t < 16; ++t) amp[sr ^ swz((unsigned)B.voff[t])] = a[t];
        __syncthreads();
    }

    if constexpr (MODE == 2) {
        // fallback (only if nbundles==0): measure from LDS
        float acc = 0.f;
        const unsigned mcp = (unsigned)(__popc((unsigned)meta.meas_nl & c) & 1);
        for (int k = 0; k < 16; ++k) {
            unsigned u = (unsigned)(tid + k * 256);
            v2f a = amp[swz(u)];
            float pr = a.x * a.x + a.y * a.y;
            acc += (((unsigned)__popc(u & (unsigned)meta.meas_row) & 1u) ^ mcp)
                 ? -pr : pr;
        }
        for (int off = 32; off > 0; off >>= 1) acc += __shfl_down(acc, off, 64);
        if ((tid & 63) == 0) atomicAdd(&out[bb], acc);
    } else {
        #pragma unroll
        for (int it = 0; it < 4; ++it) {
            unsigned u = (unsigned)(tid + it * 256) * 4u;
            unsigned ad = expand(u);
            unsigned su = swz(u);
            v2f a0 = amp[su], a1 = amp[su ^ 1u], a2 = amp[su ^ 2u], a3 = amp[su ^ 3u];
            uint4 v;
            v.x = __builtin_bit_cast(unsigned, __float22half2_rn(make_float2(a0.x, a0.y)));
            v.y = __builtin_bit_cast(unsigned, __float22half2_rn(make_float2(a1.x, a1.y)));
            v.z = __builtin_bit_cast(unsigned, __float22half2_rn(make_float2(a2.x, a2.y)));
            v.w = __builtin_bit_cast(unsigned, __float22half2_rn(make_float2(a3.x, a3.y)));
            *reinterpret_cast<uint4*>(state + base + ad) = v;
        }
    }
}

extern "C" void kernel_launch(void* const* d_in, const int* in_sizes, int n_in,
                              void* d_out, int out_size, void* d_ws, size_t ws_size,
                              hipStream_t stream)
{
    const float* X  = (const float*)d_in[0];
    const float* Wt = (const float*)d_in[1];
    const float* Bs = (const float*)d_in[2];
    float* out = (float*)d_out;
    __half2* state = (__half2*)d_ws;

    int group = 1;   // fp16 state: 256 KiB per batch element
    while (group < 512 && (size_t)(group * 2) * (65536ull * 4) <= ws_size)
        group <<= 1;
    const int ngroups = 512 / group;

    // ---- GF(2) bookkeeping (sequential CNOT ring, matches reference) ----
    uint16_t D[16], R[16];
    for (int w = 0; w < 16; ++w) { D[w] = R[w] = (uint16_t)(1u << w); }
    struct G { uint16_t D, R; uint8_t gidx; bool kept; bool sched; };
    G gl[48]; int ng = 0;
    for (int l = 1; l <= 3; ++l) {
        for (int w = 0; w < 16; ++w) { int t = (w + 1) & 15; D[w] ^= D[t]; R[t] ^= R[w]; }
        for (int w = 0; w < 16; ++w)
            gl[ng++] = G{D[w], R[w], (uint8_t)(l * 16 + w), true, false};
    }
    for (int w = 0; w < 16; ++w) { int t = (w + 1) & 15; D[w] ^= D[t]; R[t] ^= R[w]; }
    const uint16_t Rmeas = R[0];

    // Backward prune
    {
        uint16_t keptD[49], keptR[49]; int nk = 0;
        keptD[nk] = 0; keptR[nk] = Rmeas; ++nk;
        for (int i = ng - 1; i >= 0; --i) {
            bool comm = true;
            for (int k = 0; k < nk; ++k) {
                if (__builtin_parity((unsigned)(gl[i].D & keptR[k])) ||
                    __builtin_parity((unsigned)(keptD[k] & gl[i].R))) { comm = false; break; }
            }
            if (comm) gl[i].kept = false;
            else { keptD[nk] = gl[i].D; keptR[nk] = gl[i].R; ++nk; }
        }
    }
    int nkept = 0;
    for (int i = 0; i < ng; ++i) if (gl[i].kept) ++nkept;

    auto commute = [&](int i, int j) -> bool {
        return !(__builtin_parity((unsigned)(gl[i].D & gl[j].R)) ||
                 __builtin_parity((unsigned)(gl[j].D & gl[i].R)));
    };

    const int MAXP = 8;
    auto simulate = [&](uint16_t SA, uint16_t SB, int* passOf) -> int {
        for (int i = 0; i < ng; ++i) gl[i].sched = false;
        int rem = nkept, np = 0, stall = 0;
        while (rem > 0 && np < MAXP) {
            uint16_t S = (np & 1) ? SB : SA;
            int got = 0;
            for (int i = 0; i < ng; ++i) {
                if (!gl[i].kept || gl[i].sched) continue;
                if (gl[i].D & S) continue;
                bool ok = true;
                for (int j = 0; j < i; ++j) {
                    if (!gl[j].kept || gl[j].sched) continue;
                    if (!commute(i, j)) { ok = false; break; }
                }
                if (!ok) continue;
                gl[i].sched = true; --rem; ++got;
                if (passOf) passOf[i] = np;
            }
            ++np;
            if (got == 0) { if (++stall >= 2) break; } else stall = 0;
        }
        return rem == 0 ? np : 99;
    };

    // Window-pair search (4 excluded wires per window, consecutive runs)
    int bestNp = 99, bestA = 0, bestB = 8;
    for (int a = 0; a < 16; ++a) {
        for (int b = 0; b < 16; ++b) {
            uint16_t SA = 0, SB = 0;
            for (int k = 0; k < 4; ++k) {
                SA |= (uint16_t)(1u << ((a + k) & 15));
                SB |= (uint16_t)(1u << ((b + k) & 15));
            }
            int np = simulate(SA, SB, nullptr);
            if (np < bestNp) { bestNp = np; bestA = a; bestB = b; }
        }
    }
    uint16_t SA = 0, SB = 0;
    int exA[4], exB[4];
    for (int k = 0; k < 4; ++k) {
        exA[k] = (bestA + k) & 15; exB[k] = (bestB + k) & 15;
        SA |= (uint16_t)(1u << exA[k]); SB |= (uint16_t)(1u << exB[k]);
    }
    int passOf[48];
    for (int i = 0; i < ng; ++i) passOf[i] = -1;
    int np = simulate(SA, SB, passOf);
    if (np > MAXP) np = MAXP;
    if (np < 2) np = 2;

    // Wire -> bit position: all excluded wires at positions >= 8.
    int wireToPos[16]; bool used[16] = {};
    int pos = 15;
    for (int k = 0; k < 4; ++k) { wireToPos[exA[k]] = pos--; used[exA[k]] = true; }
    for (int k = 0; k < 4; ++k)
        if (!used[exB[k]]) { wireToPos[exB[k]] = pos--; used[exB[k]] = true; }
    for (int w = 0; w < 16; ++w) if (!used[w]) wireToPos[w] = pos--;
    int posToWire[16];
    for (int w = 0; w < 16; ++w) posToWire[wireToPos[w]] = w;

    PassMeta pms[8];
    for (int p = 0; p < np; ++p) {
        PassMeta& M = pms[p];
        memset(&M, 0, sizeof(M));
        const int* ex = (p & 1) ? exB : exA;
        int gp[4], gw[4];
        for (int k = 0; k < 4; ++k) { gp[k] = wireToPos[ex[k]]; gw[k] = ex[k]; }
        for (int a2 = 0; a2 < 4; ++a2)
            for (int b2 = a2 + 1; b2 < 4; ++b2)
                if (gp[b2] < gp[a2]) {
                    int t = gp[a2]; gp[a2] = gp[b2]; gp[b2] = t;
                    t = gw[a2]; gw[a2] = gw[b2]; gw[b2] = t;
                }
        for (int k = 0; k < 4; ++k) { M.gap[k] = (uint8_t)gp[k]; M.nlw[k] = (uint8_t)gw[k]; }
        int packedOfWire[16];
        for (int w = 0; w < 16; ++w) packedOfWire[w] = -1;
        int t = 0;
        for (int q = 0; q < 16; ++q) {
            bool isgap = false;
            for (int k = 0; k < 4; ++k) if (q == gp[k]) isgap = true;
            if (isgap) continue;
            M.wire_of_bit[t] = (uint8_t)posToWire[q];
            packedOfWire[posToWire[q]] = t;
            ++t;
        }
        // local gate list (schedule order; layer-major)
        struct LG { uint16_t m, r; uint8_t nl, gidx; };
        LG ls[48]; int nsel = 0;
        for (int i = 0; i < ng; ++i) {
            if (!gl[i].kept || passOf[i] != p) continue;
            uint16_t m = 0, r = 0; uint8_t nl = 0;
            for (int w = 0; w < 16; ++w) {
                if ((gl[i].D >> w) & 1) m |= (uint16_t)(1u << packedOfWire[w]);
                if (((gl[i].R >> w) & 1) && packedOfWire[w] >= 0)
                    r |= (uint16_t)(1u << packedOfWire[w]);
            }
            for (int k = 0; k < 4; ++k)
                if ((gl[i].R >> gw[k]) & 1) nl |= (uint8_t)(1u << k);
            ls[nsel++] = LG{m, r, nl, gl[i].gidx};
        }
        // Bundle: <=4 SAME-LAYER gates with independent masks (flip stays 0);
        // pads prefer bits outside the bundle's row union (clean => flip 0).
        M.nbundles = 0;
        int s = 0;
        while (s < nsel && M.nbundles < 24) {
            BundleMeta& B = M.bd[M.nbundles++];
            for (int j = 0; j < 4; ++j) {
                B.gidx[j] = 0xFF; B.row[j] = 0; B.flip[j] = 0; B.nl[j] = 0;
            }
            uint16_t red[4], om[4]; int pv[4]; int nsl = 0;
            const int lay = ls[s].gidx >> 4;
            while (nsl < 4 && s < nsel && (ls[s].gidx >> 4) == lay) {
                uint16_t r0 = ls[s].m;
                for (int j = 0; j < nsl; ++j)
                    if ((r0 >> pv[j]) & 1) r0 ^= red[j];
                if (!r0) break;    // dependent -> close bundle
                pv[nsl] = 31 - __builtin_clz((unsigned)r0);
                red[nsl] = r0; om[nsl] = ls[s].m;
                B.gidx[nsl] = ls[s].gidx; B.row[nsl] = ls[s].r; B.nl[nsl] = ls[s].nl;
                ++nsl; ++s;
            }
            uint16_t rowU = 0;
            for (int j = 0; j < nsl; ++j) rowU |= B.row[j];
            for (int pass2 = 0; pass2 < 2 && nsl < 4; ++pass2) {
                for (int b = 11; b >= 0 && nsl < 4; --b) {
                    if (pass2 == 0 && ((rowU >> b) & 1)) continue;  // prefer clean
                    uint16_t r0 = (uint16_t)(1u << b);
                    for (int j = 0; j < nsl; ++j)
                        if ((r0 >> pv[j]) & 1) r0 ^= red[j];
                    if (!r0) continue;
                    pv[nsl] = 31 - __builtin_clz((unsigned)r0);
                    red[nsl] = r0; om[nsl] = (uint16_t)(1u << b);
                    ++nsl;
                }
            }
            for (int tt = 0; tt < 16; ++tt) {
                uint16_t v = 0;
                for (int j = 0; j < 4; ++j) if ((tt >> j) & 1) v ^= om[j];
                B.voff[tt] = v;
            }
            for (int j = 0; j < 4; ++j) {
                if (B.gidx[j] == 0xFF) continue;
                uint16_t f = 0;
                for (int tt = 0; tt < 16; ++tt)
                    if (__builtin_parity((unsigned)(B.voff[tt] & B.row[j])))
                        f |= (uint16_t)(1u << tt);
                B.flip[j] = f;
            }
            for (int a2 = 0; a2 < 4; ++a2)
                for (int b2 = a2 + 1; b2 < 4; ++b2)
                    if (pv[b2] < pv[a2]) { int tt = pv[a2]; pv[a2] = pv[b2]; pv[b2] = tt; }
            for (int j = 0; j < 4; ++j) B.piv[j] = (uint8_t)pv[j];
        }
        {   // measurement masks (used only if this pass is last)
            uint16_t r = 0; uint8_t nl = 0;
            for (int w = 0; w < 16; ++w)
                if (((Rmeas >> w) & 1) && packedOfWire[w] >= 0)
                    r |= (uint16_t)(1u << packedOfWire[w]);
            for (int k = 0; k < 4; ++k)
                if ((Rmeas >> gw[k]) & 1) nl |= (uint8_t)(1u << k);
            M.meas_row = r; M.meas_nl = nl;
        }
    }

    for (int g = 0; g < ngroups; ++g) {
        const float* Xg = X + (size_t)g * group * 16;
        float* og = out + (size_t)g * group;
        dim3 grid((unsigned)(group << 4));
        for (int p = 0; p < np; ++p) {
            int mode = (p == 0) ? 0 : ((p == np - 1) ? 2 : 1);
            if (mode == 0)
                pass_kernel<0><<<grid, dim3(256), 0, stream>>>(Xg, Wt, Bs, state, og, pms[p]);
            else if (mode == 1)
                pass_kernel<1><<<grid, dim3(256), 0, stream>>>(Xg, Wt, Bs, state, og, pms[p]);
            else
                pass_kernel<2><<<grid, dim3(256), 0, stream>>>(Xg, Wt, Bs, state, og, pms[p]);
        }
    }

    (void)in_sizes; (void)n_in; (void)out_size; (void)ws_size;
}

// Round 11
// 576.699 us; speedup vs baseline: 1.0294x; 1.0294x over previous
//
#include <hip/hip_runtime.h>
#include <hip/hip_fp16.h>
#include <cstdint>
#include <cstring>

// VQR circuit simulator: 16 qubits, B=512, 4 layers.
// CNOTs are GF(2) index-relabeling bookkeeping. Fused 1q gates (SU(2)) are
// XOR-mask pair rotations, scheduled into 2 window passes. LDS layout packs
// adjacent amps (local bit 0) as float4 {re0,re1,im0,im1}: one b128 per
// 2 amps, and gate math runs on packed (2-amp) registers via v_pk_fma_f32:
// 8 FMA-instr per pair (vs 16 scalar). Signs: per-slot-pair fpar + lane
// sign (row&1) -- exact for ANY bundle composition. Gates whose mask hits
// local bit 0 (rare: position-0 wire = argmin D-usage) use the proven
// scalar path on register lanes (free lane access: v2f = 2 VGPRs).

typedef float v2f __attribute__((ext_vector_type(2)));

struct BundleMeta {
    uint16_t voffH[8];   // slot offsets, amp-index>>1 (bit0-free by construction)
    uint16_t grow[4];    // branch parity masks (local bits); slot3 = e0 gate
    uint8_t  gfpar[4];   // bit t = parity(voffE[t] & row)
    uint8_t  gnl[4];     // chunk-bit parity masks
    uint8_t  ggidx[4];   // coefficient index l*16+w; 0xFF = empty slot
    uint8_t  glf[4];     // mask bit0 (lane flip) -> scalar path
    uint8_t  piv[4];     // expansion pivots ASC; piv[0]==0 (lane axis)
};

struct PassMeta {
    int        nbundles;
    BundleMeta bd[24];
    uint8_t    gap[4];          // non-local bit positions, ASC (all >=8)
    uint8_t    nlw[4];          // chunk bit k -> wire
    uint8_t    wire_of_bit[12]; // local bit -> wire (product-state init)
    uint16_t   meas_row;        // measurement parity mask (local bits)
    uint8_t    meas_nl;         // measurement parity mask (chunk bits)
};

__device__ __forceinline__ float2 cmul2(float2 a, float2 b) {
    return make_float2(a.x * b.x - a.y * b.y, a.x * b.y + a.y * b.x);
}
__device__ __forceinline__ float xorf(float a, unsigned s) {
    return __uint_as_float(__float_as_uint(a) ^ s);
}

// MODE 0: coef + product state + gates + store (fp16)
// MODE 1: coef + load + gates + store (in-place, fp16)
// MODE 2: coef + load + gates + measurement reduce (no store)
template <int MODE>
__global__ __launch_bounds__(256, 4)
void pass_kernel(const float* __restrict__ X, const float* __restrict__ Wt,
                 const float* __restrict__ Bs, __half2* __restrict__ state,
                 float* __restrict__ out, PassMeta meta)
{
    __shared__ float4 ampq[2048];  // 32 KiB: pair p -> {re0,re1,im0,im1}
    __shared__ float4 coef[64];    // 1 KiB   (SU(2) (a,b) per gate)
    const int tid = threadIdx.x;
    const int bb  = blockIdx.x >> 4;
    const unsigned c = blockIdx.x & 15u;
    const size_t base = (size_t)bb << 16;

    // ---- in-block coefficients: U = Rz(t2)Ry(t1)Rz(t0)Rx(2atan x), SU(2) (a,b)
    if (tid < 64) {
        int l = tid >> 4, w = tid & 15;
        float x  = X[bb * 16 + w];
        float ce = 1.0f / sqrtf(1.0f + x * x);
        float se = x * ce;
        float t0 = 0.5f * Wt[(l * 16 + w) * 3 + 0];
        float t1 = 0.5f * Wt[(l * 16 + w) * 3 + 1];
        float t2 = 0.5f * Wt[(l * 16 + w) * 3 + 2];
        float c1 = cosf(t1), s1 = sinf(t1);
        float ca = cosf(t0 + t2), sa = sinf(t0 + t2);
        float cb = cosf(t2 - t0), sb = sinf(t2 - t0);
        float2 W00 = make_float2( c1 * ca, -c1 * sa);
        float2 W01 = make_float2(-s1 * cb,  s1 * sb);
        float2 a  = make_float2(W00.x * ce + W01.y * se, W00.y * ce - W01.x * se);
        float2 b2 = make_float2(W00.y * se + W01.x * ce, -W00.x * se + W01.y * ce);
        coef[tid] = make_float4(a.x, a.y, b2.x, b2.y);
    }
    if (MODE == 0 && c == 0 && tid == 64) out[bb] = Bs[0];  // bias init

    auto expand = [&](unsigned x) -> unsigned {   // gaps ascending, all >= 8
        #pragma unroll
        for (int k = 0; k < 4; ++k) {
            unsigned g = meta.gap[k];
            x = ((x >> g) << (g + 1)) | (x & ((1u << g) - 1u)) | (((c >> k) & 1u) << g);
        }
        return x;
    };

    float* f = reinterpret_cast<float*>(ampq);   // RE(i)=f[2(i&~1)+(i&1)], IM at +2

    if constexpr (MODE == 0) {
        __syncthreads();   // coef ready
        if (tid == 0) {
            float2 k = make_float2(1.f, 0.f);
            #pragma unroll
            for (int t = 0; t < 4; ++t) {
                float4 u = coef[meta.nlw[t]];
                float2 col = ((c >> t) & 1u) ? make_float2(-u.z, u.w)
                                             : make_float2(u.x, u.y);
                k = cmul2(k, col);
            }
            f[0] = k.x; f[2] = k.y;
        }
        __syncthreads();
        for (int s = 0; s < 12; ++s) {
            const int n = 1 << s;
            float4 u = coef[meta.wire_of_bit[s]];
            const float2 c0 = make_float2(u.x, u.y);
            const float2 c1 = make_float2(-u.z, u.w);
            for (int i = tid; i < n; i += 256) {
                unsigned b = (unsigned)i & ~1u, l = (unsigned)i & 1u;
                float2 a = make_float2(f[2*b + l], f[2*b + 2 + l]);
                float2 h = cmul2(a, c1);
                float2 lo = cmul2(a, c0);
                unsigned j = (unsigned)(i + n), jb = j & ~1u, jl = j & 1u;
                f[2*jb + jl] = h.x; f[2*jb + 2 + jl] = h.y;
                f[2*b + l] = lo.x;  f[2*b + 2 + l] = lo.y;
            }
            __syncthreads();
        }
    } else {
        #pragma unroll
        for (int it = 0; it < 4; ++it) {
            unsigned u = (unsigned)(tid + it * 256) * 4u;
            unsigned a = expand(u);
            uint4 v = *reinterpret_cast<const uint4*>(state + base + a);
            float2 f0 = __half22float2(__builtin_bit_cast(__half2, v.x));
            float2 f1 = __half22float2(__builtin_bit_cast(__half2, v.y));
            float2 f2 = __half22float2(__builtin_bit_cast(__half2, v.z));
            float2 f3 = __half22float2(__builtin_bit_cast(__half2, v.w));
            ampq[(u >> 1)]     = make_float4(f0.x, f1.x, f0.y, f1.y);
            ampq[(u >> 1) + 1] = make_float4(f2.x, f3.x, f2.y, f3.y);
        }
        __syncthreads();   // also covers coef staging
    }

    for (int ci = 0; ci < meta.nbundles; ++ci) {
        const BundleMeta& B = meta.bd[ci];
        unsigned r = (unsigned)tid;
        #pragma unroll
        for (int k = 0; k < 4; ++k) {
            unsigned p = B.piv[k];
            r = ((r >> p) << (p + 1)) | (r & ((1u << p) - 1u));
        }
        const unsigned rh = r >> 1;
        v2f RE[8], IM[8];
        #pragma unroll
        for (int t = 0; t < 8; ++t) {
            float4 q = ampq[rh ^ (unsigned)B.voffH[t]];
            RE[t] = v2f{q.x, q.y}; IM[t] = v2f{q.z, q.w};
        }
        auto sc = [&](float& pr, float& pi, float& qr, float& qi,
                      float ax, float by, float tai, float tbr) {
            float npr = __builtin_fmaf(ax, pr, __builtin_fmaf(-tai, pi,
                        __builtin_fmaf(tbr, qr, -by * qi)));
            float npi = __builtin_fmaf(ax, pi, __builtin_fmaf( tai, pr,
                        __builtin_fmaf(tbr, qi,  by * qr)));
            float nqr = __builtin_fmaf(-tbr, pr, __builtin_fmaf(-by, pi,
                        __builtin_fmaf(ax, qr,  tai * qi)));
            float nqi = __builtin_fmaf(-tbr, pi, __builtin_fmaf( by, pr,
                        __builtin_fmaf(ax, qi, -tai * qr)));
            pr = npr; pi = npi; qr = nqr; qi = nqi;
        };
        // slot 3 (e0 gate, in-slot cross-lane) applied FIRST (host guarantees order)
        if (B.ggidx[3] != 0xFF) {
            const float4 uv = coef[B.ggidx[3]];
            const unsigned row = B.grow[3];
            const unsigned sb31 = ((unsigned)((__popc(r & row) +
                __popc((unsigned)B.gnl[3] & c)) & 1)) << 31;
            const float ai_s = xorf(uv.y, sb31), br_s = xorf(uv.z, sb31);
            const unsigned fp = B.gfpar[3];
            #pragma unroll
            for (int t = 0; t < 8; ++t) {
                const unsigned f31 = ((fp >> t) & 1u) << 31;
                const float tai = xorf(ai_s, f31), tbr = xorf(br_s, f31);
                float pr = RE[t].x, pi = IM[t].x, qr = RE[t].y, qi = IM[t].y;
                sc(pr, pi, qr, qi, uv.x, uv.w, tai, tbr);
                RE[t].x = pr; IM[t].x = pi; RE[t].y = qr; IM[t].y = qi;
            }
        }
        #pragma unroll
        for (int g = 0; g < 3; ++g) {
            if (B.ggidx[g] == 0xFF) continue;
            const float4 uv = coef[B.ggidx[g]];
            const unsigned row = B.grow[g];
            const unsigned sb31 = ((unsigned)((__popc(r & row) +
                __popc((unsigned)B.gnl[g] & c)) & 1)) << 31;
            const float ai_s = xorf(uv.y, sb31), br_s = xorf(uv.z, sb31);
            const unsigned fp = B.gfpar[g];
            if (!B.glf[g]) {
                // PACKED: both lanes simultaneously; lane1 sign differs iff row&1
                const unsigned ro31 = (row & 1u) << 31;
                const v2f ARv = {uv.x, uv.x}, BIv = {uv.w, uv.w};
                #pragma unroll
                for (int t = 0; t < 8; ++t) {
                    if (t & (1 << g)) continue;
                    const int t2 = t | (1 << g);
                    const unsigned f31 = ((fp >> t) & 1u) << 31;
                    const v2f TAI = { xorf(ai_s, f31), xorf(ai_s, f31 ^ ro31) };
                    const v2f TBR = { xorf(br_s, f31), xorf(br_s, f31 ^ ro31) };
                    const v2f PR = RE[t], PI = IM[t], QR = RE[t2], QI = IM[t2];
                    RE[t]  = ARv * PR - TAI * PI + TBR * QR - BIv * QI;
                    IM[t]  = ARv * PI + TAI * PR + TBR * QI + BIv * QR;
                    RE[t2] = -(TBR * PR) - BIv * PI + ARv * QR + TAI * QI;
                    IM[t2] = -(TBR * PI) + BIv * PR + ARv * QI - TAI * QR;
                }
            } else {
                // SCALAR cross-lane: (t,l0)<->(t2,l1) and (t2,l0)<->(t,l1)
                #pragma unroll
                for (int t = 0; t < 8; ++t) {
                    if (t & (1 << g)) continue;
                    const int t2 = t | (1 << g);
                    {
                        const unsigned f31 = ((fp >> t) & 1u) << 31;
                        const float tai = xorf(ai_s, f31), tbr = xorf(br_s, f31);
                        float pr = RE[t].x, pi = IM[t].x;
                        float qr = RE[t2].y, qi = IM[t2].y;
                        sc(pr, pi, qr, qi, uv.x, uv.w, tai, tbr);
                        RE[t].x = pr; IM[t].x = pi; RE[t2].y = qr; IM[t2].y = qi;
                    }
                    {
                        const unsigned f31 = ((fp >> t2) & 1u) << 31;
                        const float tai = xorf(ai_s, f31), tbr = xorf(br_s, f31);
                        float pr = RE[t2].x, pi = IM[t2].x;
                        float qr = RE[t].y, qi = IM[t].y;
                        sc(pr, pi, qr, qi, uv.x, uv.w, tai, tbr);
                        RE[t2].x = pr; IM[t2].x = pi; RE[t].y = qr; IM[t].y = qi;
                    }
                }
            }
        }
        if (MODE == 2 && ci == meta.nbundles - 1) {
            float acc = 0.f;
            const unsigned mrow = meta.meas_row;
            const unsigned ml31 = (mrow & 1u) << 31;
            const unsigned mcp = (unsigned)(__popc((unsigned)meta.meas_nl & c) & 1);
            #pragma unroll
            for (int t = 0; t < 8; ++t) {
                unsigned ie = r ^ ((unsigned)B.voffH[t] << 1);
                unsigned s031 = (((unsigned)__popc(ie & mrow) & 1u) ^ mcp) << 31;
                v2f pr = RE[t] * RE[t] + IM[t] * IM[t];
                acc += xorf(pr.x, s031) + xorf(pr.y, s031 ^ ml31);
            }
            for (int off = 32; off > 0; off >>= 1) acc += __shfl_down(acc, off, 64);
            if ((tid & 63) == 0) atomicAdd(&out[bb], acc);
            return;
        }
        #pragma unroll
        for (int t = 0; t < 8; ++t)
            ampq[rh ^ (unsigned)B.voffH[t]] =
                make_float4(RE[t].x, RE[t].y, IM[t].x, IM[t].y);
        __syncthreads();
    }

    if constexpr (MODE == 2) {
        // fallback (only if nbundles==0): measure from LDS
        float acc = 0.f;
        const unsigned mcp = (unsigned)(__popc((unsigned)meta.meas_nl & c) & 1);
        for (int k = 0; k < 16; ++k) {
            unsigned u = (unsigned)(tid + k * 256);
            unsigned b = u & ~1u, l = u & 1u;
            float re = f[2*b + l], im = f[2*b + 2 + l];
            float pr = re * re + im * im;
            acc += (((unsigned)__popc(u & (unsigned)meta.meas_row) & 1u) ^ mcp)
                 ? -pr : pr;
        }
        for (int off = 32; off > 0; off >>= 1) acc += __shfl_down(acc, off, 64);
        if ((tid & 63) == 0) atomicAdd(&out[bb], acc);
    } else {
        #pragma unroll
        for (int it = 0; it < 4; ++it) {
            unsigned u = (unsigned)(tid + it * 256) * 4u;
            unsigned ad = expand(u);
            float4 q0 = ampq[(u >> 1)];
            float4 q1 = ampq[(u >> 1) + 1];
            uint4 v;
            v.x = __builtin_bit_cast(unsigned, __float22half2_rn(make_float2(q0.x, q0.z)));
            v.y = __builtin_bit_cast(unsigned, __float22half2_rn(make_float2(q0.y, q0.w)));
            v.z = __builtin_bit_cast(unsigned, __float22half2_rn(make_float2(q1.x, q1.z)));
            v.w = __builtin_bit_cast(unsigned, __float22half2_rn(make_float2(q1.y, q1.w)));
            *reinterpret_cast<uint4*>(state + base + ad) = v;
        }
    }
}

extern "C" void kernel_launch(void* const* d_in, const int* in_sizes, int n_in,
                              void* d_out, int out_size, void* d_ws, size_t ws_size,
                              hipStream_t stream)
{
    const float* X  = (const float*)d_in[0];
    const float* Wt = (const float*)d_in[1];
    const float* Bs = (const float*)d_in[2];
    float* out = (float*)d_out;
    __half2* state = (__half2*)d_ws;

    int group = 1;   // fp16 state: 256 KiB per batch element
    while (group < 512 && (size_t)(group * 2) * (65536ull * 4) <= ws_size)
        group <<= 1;
    const int ngroups = 512 / group;

    // ---- GF(2) bookkeeping (sequential CNOT ring, matches reference) ----
    uint16_t D[16], R[16];
    for (int w = 0; w < 16; ++w) { D[w] = R[w] = (uint16_t)(1u << w); }
    struct G { uint16_t D, R; uint8_t gidx; bool kept; bool sched; };
    G gl[48]; int ng = 0;
    for (int l = 1; l <= 3; ++l) {
        for (int w = 0; w < 16; ++w) { int t = (w + 1) & 15; D[w] ^= D[t]; R[t] ^= R[w]; }
        for (int w = 0; w < 16; ++w)
            gl[ng++] = G{D[w], R[w], (uint8_t)(l * 16 + w), true, false};
    }
    for (int w = 0; w < 16; ++w) { int t = (w + 1) & 15; D[w] ^= D[t]; R[t] ^= R[w]; }
    const uint16_t Rmeas = R[0];

    // Backward prune
    {
        uint16_t keptD[49], keptR[49]; int nk = 0;
        keptD[nk] = 0; keptR[nk] = Rmeas; ++nk;
        for (int i = ng - 1; i >= 0; --i) {
            bool comm = true;
            for (int k = 0; k < nk; ++k) {
                if (__builtin_parity((unsigned)(gl[i].D & keptR[k])) ||
                    __builtin_parity((unsigned)(keptD[k] & gl[i].R))) { comm = false; break; }
            }
            if (comm) gl[i].kept = false;
            else { keptD[nk] = gl[i].D; keptR[nk] = gl[i].R; ++nk; }
        }
    }
    int nkept = 0;
    for (int i = 0; i < ng; ++i) if (gl[i].kept) ++nkept;

    auto commute = [&](int i, int j) -> bool {
        return !(__builtin_parity((unsigned)(gl[i].D & gl[j].R)) ||
                 __builtin_parity((unsigned)(gl[j].D & gl[i].R)));
    };

    const int MAXP = 8;
    auto simulate = [&](uint16_t SA, uint16_t SB, int* passOf) -> int {
        for (int i = 0; i < ng; ++i) gl[i].sched = false;
        int rem = nkept, np = 0, stall = 0;
        while (rem > 0 && np < MAXP) {
            uint16_t S = (np & 1) ? SB : SA;
            int got = 0;
            for (int i = 0; i < ng; ++i) {
                if (!gl[i].kept || gl[i].sched) continue;
                if (gl[i].D & S) continue;
                bool ok = true;
                for (int j = 0; j < i; ++j) {
                    if (!gl[j].kept || gl[j].sched) continue;
                    if (!commute(i, j)) { ok = false; break; }
                }
                if (!ok) continue;
                gl[i].sched = true; --rem; ++got;
                if (passOf) passOf[i] = np;
            }
            ++np;
            if (got == 0) { if (++stall >= 2) break; } else stall = 0;
        }
        return rem == 0 ? np : 99;
    };

    // Window-pair search (4 excluded wires per window, consecutive runs)
    int bestNp = 99, bestA = 0, bestB = 8;
    for (int a = 0; a < 16; ++a) {
        for (int b = 0; b < 16; ++b) {
            uint16_t SA = 0, SB = 0;
            for (int k = 0; k < 4; ++k) {
                SA |= (uint16_t)(1u << ((a + k) & 15));
                SB |= (uint16_t)(1u << ((b + k) & 15));
            }
            int np = simulate(SA, SB, nullptr);
            if (np < bestNp) { bestNp = np; bestA = a; bestB = b; }
        }
    }
    uint16_t SA = 0, SB = 0;
    int exA[4], exB[4];
    for (int k = 0; k < 4; ++k) {
        exA[k] = (bestA + k) & 15; exB[k] = (bestB + k) & 15;
        SA |= (uint16_t)(1u << exA[k]); SB |= (uint16_t)(1u << exB[k]);
    }
    int passOf[48];
    for (int i = 0; i < ng; ++i) passOf[i] = -1;
    int np = simulate(SA, SB, passOf);
    if (np > MAXP) np = MAXP;
    if (np < 2) np = 2;

    // Wire -> position: excluded wires at >=8; position 0 = wire with FEWEST
    // D-appearances (minimizes lane-flip scalar-path gates).
    int wireToPos[16]; bool used[16] = {};
    int pos = 15;
    for (int k = 0; k < 4; ++k) { wireToPos[exA[k]] = pos--; used[exA[k]] = true; }
    for (int k = 0; k < 4; ++k)
        if (!used[exB[k]]) { wireToPos[exB[k]] = pos--; used[exB[k]] = true; }
    int cntD[16] = {0};
    for (int i = 0; i < ng; ++i)
        if (gl[i].kept)
            for (int w = 0; w < 16; ++w)
                if ((gl[i].D >> w) & 1) cntD[w]++;
    int w0 = -1, bestC = 1 << 30;
    for (int w = 0; w < 16; ++w)
        if (!used[w] && cntD[w] < bestC) { bestC = cntD[w]; w0 = w; }
    for (int w = 0; w < 16; ++w)
        if (!used[w] && w != w0) wireToPos[w] = pos--;
    wireToPos[w0] = pos--;   // == 0
    int posToWire[16];
    for (int w = 0; w < 16; ++w) posToWire[wireToPos[w]] = w;

    PassMeta pms[8];
    for (int p = 0; p < np; ++p) {
        PassMeta& M = pms[p];
        memset(&M, 0, sizeof(M));
        const int* ex = (p & 1) ? exB : exA;
        int gp[4], gw[4];
        for (int k = 0; k < 4; ++k) { gp[k] = wireToPos[ex[k]]; gw[k] = ex[k]; }
        for (int a2 = 0; a2 < 4; ++a2)
            for (int b2 = a2 + 1; b2 < 4; ++b2)
                if (gp[b2] < gp[a2]) {
                    int t = gp[a2]; gp[a2] = gp[b2]; gp[b2] = t;
                    t = gw[a2]; gw[a2] = gw[b2]; gw[b2] = t;
                }
        for (int k = 0; k < 4; ++k) { M.gap[k] = (uint8_t)gp[k]; M.nlw[k] = (uint8_t)gw[k]; }
        int packedOfWire[16];
        for (int w = 0; w < 16; ++w) packedOfWire[w] = -1;
        int t = 0;
        for (int q = 0; q < 16; ++q) {
            bool isgap = false;
            for (int k = 0; k < 4; ++k) if (q == gp[k]) isgap = true;
            if (isgap) continue;
            M.wire_of_bit[t] = (uint8_t)posToWire[q];
            packedOfWire[posToWire[q]] = t;
            ++t;
        }
        // local gate list in schedule order
        struct LG { uint16_t m, r; uint8_t nl, gidx; };
        LG ls[48]; int nsel = 0;
        for (int i = 0; i < ng; ++i) {
            if (!gl[i].kept || passOf[i] != p) continue;
            uint16_t m = 0, r = 0; uint8_t nl = 0;
            for (int w = 0; w < 16; ++w) {
                if ((gl[i].D >> w) & 1) m |= (uint16_t)(1u << packedOfWire[w]);
                if (((gl[i].R >> w) & 1) && packedOfWire[w] >= 0)
                    r |= (uint16_t)(1u << packedOfWire[w]);
            }
            for (int k = 0; k < 4; ++k)
                if ((gl[i].R >> gw[k]) & 1) nl |= (uint8_t)(1u << k);
            ls[nsel++] = LG{m, r, nl, gl[i].gidx};
        }
        // Bundle: greedy basis of 3 bit0-free masks (+ optional leading e0 gate).
        M.nbundles = 0;
        int s = 0;
        while (s < nsel && M.nbundles < 24) {
            BundleMeta& B = M.bd[M.nbundles++];
            memset(&B, 0, sizeof(B));
            for (int j = 0; j < 4; ++j) B.ggidx[j] = 0xFF;
            uint16_t red[3], om[3]; int pv[3]; int nb = 0;
            bool any = false;
            while (s < nsel) {
                uint16_t m = ls[s].m;
                uint16_t mp = (uint16_t)(m & ~1u);
                int lf = m & 1;
                if (mp == 0) {     // mask == e0 exactly
                    if (any) break;
                    B.ggidx[3] = ls[s].gidx; B.grow[3] = ls[s].r;
                    B.gnl[3] = ls[s].nl; B.glf[3] = 1;
                    any = true; ++s; continue;
                }
                uint16_t rem = mp;
                for (int j = 0; j < nb; ++j)
                    if ((rem >> pv[j]) & 1) rem ^= red[j];
                if (rem == 0) break;     // dependent -> close bundle
                if (nb == 3) break;
                pv[nb] = 31 - __builtin_clz((unsigned)rem);
                red[nb] = rem; om[nb] = mp;
                B.ggidx[nb] = ls[s].gidx; B.grow[nb] = ls[s].r;
                B.gnl[nb] = ls[s].nl; B.glf[nb] = (uint8_t)lf;
                ++nb; any = true; ++s;
            }
            for (int b = 11; b >= 1 && nb < 3; --b) {   // pad basis (never bit 0)
                uint16_t rem = (uint16_t)(1u << b);
                for (int j = 0; j < nb; ++j)
                    if ((rem >> pv[j]) & 1) rem ^= red[j];
                if (!rem) continue;
                pv[nb] = 31 - __builtin_clz((unsigned)rem);
                red[nb] = rem; om[nb] = (uint16_t)(1u << b);
                ++nb;
            }
            for (int tt = 0; tt < 8; ++tt) {
                uint16_t v = 0;
                for (int j = 0; j < 3; ++j) if ((tt >> j) & 1) v ^= om[j];
                B.voffH[tt] = (uint16_t)(v >> 1);
            }
            for (int j = 0; j < 4; ++j) {
                if (B.ggidx[j] == 0xFF) continue;
                uint8_t fbits = 0;
                for (int tt = 0; tt < 8; ++tt)
                    if (__builtin_parity((unsigned)(((unsigned)B.voffH[tt] << 1)
                                                    & B.grow[j])))
                        fbits |= (uint8_t)(1u << tt);
                B.gfpar[j] = fbits;
            }
            for (int a2 = 0; a2 < 3; ++a2)
                for (int b2 = a2 + 1; b2 < 3; ++b2)
                    if (pv[b2] < pv[a2]) { int tt = pv[a2]; pv[a2] = pv[b2]; pv[b2] = tt; }
            B.piv[0] = 0;
            for (int j = 0; j < 3; ++j) B.piv[j + 1] = (uint8_t)pv[j];
            if (!any) { M.nbundles--; break; }   // safety
        }
        {   // measurement masks (used only if this pass is last)
            uint16_t r = 0; uint8_t nl = 0;
            for (int w = 0; w < 16; ++w)
                if (((Rmeas >> w) & 1) && packedOfWire[w] >= 0)
                    r |= (uint16_t)(1u << packedOfWire[w]);
            for (int k = 0; k < 4; ++k)
                if ((Rmeas >> gw[k]) & 1) nl |= (uint8_t)(1u << k);
            M.meas_row = r; M.meas_nl = nl;
        }
    }

    for (int g = 0; g < ngroups; ++g) {
        const float* Xg = X + (size_t)g * group * 16;
        float* og = out + (size_t)g * group;
        dim3 grid((unsigned)(group << 4));
        for (int p = 0; p < np; ++p) {
            int mode = (p == 0) ? 0 : ((p == np - 1) ? 2 : 1);
            if (mode == 0)
                pass_kernel<0><<<grid, dim3(256), 0, stream>>>(Xg, Wt, Bs, state, og, pms[p]);
            else if (mode == 1)
                pass_kernel<1><<<grid, dim3(256), 0, stream>>>(Xg, Wt, Bs, state, og, pms[p]);
            else
                pass_kernel<2><<<grid, dim3(256), 0, stream>>>(Xg, Wt, Bs, state, og, pms[p]);
        }
    }

    (void)in_sizes; (void)n_in; (void)out_size; (void)ws_size;
}